// Round 5
// baseline (848.911 us; speedup 1.0000x reference)
//
#include <hip/hip_runtime.h>
#include <hip/hip_bf16.h>
#include <math.h>

#define B_ 16
#define L_ 2048
#define H_ 768
#define INNER_ 384
#define MU_MAX_ 10.0f
#define LAM_ 0.1f
#define EDGES_ (2 * L_ - 3)   // 4093

typedef short v8bf __attribute__((ext_vector_type(8)));   // 8 bf16 (4 VGPRs)
typedef float v4f  __attribute__((ext_vector_type(4)));   // MFMA accumulator

static __device__ __forceinline__ float wave_sum(float v) {
    #pragma unroll
    for (int o = 32; o > 0; o >>= 1) v += __shfl_xor(v, o, 64);
    return v;
}

static __device__ __forceinline__ float dot4(const float4& a, const float4& b) {
    return a.x * b.x + a.y * b.y + a.z * b.z + a.w * b.w;
}

static __device__ __forceinline__ void fma4(float4& a, float c, float4 x) {
    a.x = fmaf(c, x.x, a.x); a.y = fmaf(c, x.y, a.y);
    a.z = fmaf(c, x.z, a.z); a.w = fmaf(c, x.w, a.w);
}

// round-to-nearest-even fp32 -> bf16 (matches numpy/JAX casting)
static __device__ __forceinline__ ushort f2bf(float x) {
    unsigned u = __float_as_uint(x);
    u += 0x7fffu + ((u >> 16) & 1u);
    return (ushort)(u >> 16);
}

// ---------------- convert + transpose wq (K x N fp32) -> wt (N x K bf16) -------
__global__ __launch_bounds__(256) void conv_wqt_kernel(
    const float* __restrict__ wq, ushort* __restrict__ wt)
{
    __shared__ float tile[64][65];
    int k0 = blockIdx.x * 64, n0 = blockIdx.y * 64;
    int t = threadIdx.x;
    #pragma unroll
    for (int it = 0; it < 16; ++it) {
        int lin = t + it * 256;
        int r = lin >> 6, c = lin & 63;         // r: k, c: n  (coalesced read)
        tile[r][c] = wq[(size_t)(k0 + r) * H_ + n0 + c];
    }
    __syncthreads();
    #pragma unroll
    for (int it = 0; it < 16; ++it) {
        int lin = t + it * 256;
        int r = lin >> 6, c = lin & 63;         // r: n, c: k  (coalesced write)
        wt[(size_t)(n0 + r) * H_ + k0 + c] = f2bf(tile[c][r]);
    }
}

// ---------------- MFMA GEMM: q = bf16(A32) @ wt^T + bq ----------------
// XCD-co-located 1D grid: idx&7 = XCD; the 6 n-blocks of one A m-tile have
// indices {c+8j} -> same XCD, temporally adjacent -> A panel HBM-fetched once.
// B (Wt, 1.2 MB, L2-hot) is read directly from global; only A is LDS-staged,
// with next-tile register prefetch issued before the MFMA phase (T14).
#define GBM 128
#define GBN 128
#define GBK 64
#define LSTR 72   // padded LDS row stride in bf16

__global__ __launch_bounds__(256) void gemm_q_kernel(
    const float* __restrict__ A32, const ushort* __restrict__ Wt,
    const float* __restrict__ bias, float* __restrict__ C)
{
    __shared__ ushort As[GBM * LSTR];            // 18432 B
    const int K = H_, N = H_;
    int idx = blockIdx.x;
    int c = idx & 7, rest = idx >> 3;            // rest 0..191 per XCD
    int n0 = (rest % 6) * GBN;
    int m0 = ((rest / 6) * 8 + c) * GBM;         // m-tile pinned to XCD c
    int t = threadIdx.x;
    int lane = t & 63, w = t >> 6;
    int wm = (w & 1) * 64, wn = (w >> 1) * 64;
    int row16 = lane & 15, quad = lane >> 4;

    v4f acc[4][4];
    #pragma unroll
    for (int i = 0; i < 4; ++i)
        #pragma unroll
        for (int j = 0; j < 4; ++j)
            acc[i][j] = (v4f){0.f, 0.f, 0.f, 0.f};

    // per-thread A staging slot: row r, 32B segment s
    int r = t >> 1;                              // 0..127  (2 threads/row)
    int sseg = (t & 1) * 4;                      // float4 index 0 or 4... see below
    // Each thread stages 2 rows x ... simpler: 4 its of (r=lin>>3, s=lin&7)
    float4 pf0[4], pf1[4];
    #pragma unroll
    for (int it = 0; it < 4; ++it) {
        int lin = t + it * 256;
        int rr = lin >> 3, s = lin & 7;
        const float* ap = A32 + (size_t)(m0 + rr) * K + s * 8;
        pf0[it] = *(const float4*)ap;
        pf1[it] = *(const float4*)(ap + 4);
    }

    for (int kt = 0; kt < 12; ++kt) {
        int k0 = kt * GBK;
        // write prefetched tile to LDS (convert fp32->bf16)
        #pragma unroll
        for (int it = 0; it < 4; ++it) {
            int lin = t + it * 256;
            int rr = lin >> 3, s = lin & 7;
            ushort tmp[8] = { f2bf(pf0[it].x), f2bf(pf0[it].y), f2bf(pf0[it].z), f2bf(pf0[it].w),
                              f2bf(pf1[it].x), f2bf(pf1[it].y), f2bf(pf1[it].z), f2bf(pf1[it].w) };
            *(v8bf*)&As[rr * LSTR + s * 8] = *(v8bf*)tmp;
        }
        // issue next-tile loads (latency hides under MFMA phase)
        if (kt < 11) {
            #pragma unroll
            for (int it = 0; it < 4; ++it) {
                int lin = t + it * 256;
                int rr = lin >> 3, s = lin & 7;
                const float* ap = A32 + (size_t)(m0 + rr) * K + (k0 + GBK) + s * 8;
                pf0[it] = *(const float4*)ap;
                pf1[it] = *(const float4*)(ap + 4);
            }
        }
        __syncthreads();
        #pragma unroll
        for (int h = 0; h < 2; ++h) {
            v8bf af[4], bf[4];
            #pragma unroll
            for (int i = 0; i < 4; ++i)
                af[i] = *(v8bf*)&As[(wm + i * 16 + row16) * LSTR + h * 32 + quad * 8];
            #pragma unroll
            for (int j = 0; j < 4; ++j)
                bf[j] = *(const v8bf*)(Wt + (size_t)(n0 + wn + j * 16 + row16) * K
                                       + k0 + h * 32 + quad * 8);
            #pragma unroll
            for (int i = 0; i < 4; ++i)
                #pragma unroll
                for (int j = 0; j < 4; ++j)
                    acc[i][j] = __builtin_amdgcn_mfma_f32_16x16x32_bf16(
                        af[i], bf[j], acc[i][j], 0, 0, 0);
        }
        __syncthreads();
    }
    #pragma unroll
    for (int j = 0; j < 4; ++j) {
        int ncol = n0 + wn + j * 16 + row16;
        float bqv = bias[ncol];
        #pragma unroll
        for (int i = 0; i < 4; ++i) {
            int mrow = m0 + wm + i * 16 + quad * 4;
            #pragma unroll
            for (int rr = 0; rr < 4; ++rr)
                C[(size_t)(mrow + rr) * N + ncol] = acc[i][j][rr] + bqv;
        }
    }
}

// ---------------- mu: one wave per 4 rows, batched MLPs -----------------------
// Rows t0..t0+3 own 8 edges (4x m1, 4x m2), needing rows t0..t0+5 (clamped).
// All 14 norm/dot reductions pipeline together; the 8 MLPs run in ONE pass
// over INNER with 8 independent accumulators, then 8 pipelined wave_sums.
// Per-edge op order (k-ascending fma chain, wave_sum tree, softplus) is
// identical to the original mu_mlp2 path.
__global__ __launch_bounds__(256) void mu_quad_kernel(
    const float* __restrict__ src,
    const float* __restrict__ w1, const float* __restrict__ b1,
    const float* __restrict__ w2, const float* __restrict__ b2,
    float* __restrict__ mu)
{
    int blk = blockIdx.x;
    int chunk = (blk & 7) * ((B_ * L_ / 16) / 8) + (blk >> 3);  // XCD-contiguous
    int b = chunk >> 7;                       // 128 blocks per batch
    int p0 = (chunk & 127) * 16;
    int w = threadIdx.x >> 6, lane = threadIdx.x & 63;
    int t0 = p0 + 4 * w;

    const float* sB = src + (size_t)b * L_ * H_;
    const float4* rp[6];
    #pragma unroll
    for (int j = 0; j < 6; ++j)
        rp[j] = (const float4*)(sB + (size_t)min(t0 + j, L_ - 1) * H_);

    float ss[6] = {0.f, 0.f, 0.f, 0.f, 0.f, 0.f};
    float d1[4] = {0.f, 0.f, 0.f, 0.f};
    float d2[4] = {0.f, 0.f, 0.f, 0.f};
    #pragma unroll
    for (int ch = 0; ch < 3; ++ch) {
        int off = ch * 64 + lane;
        float4 x[6];
        #pragma unroll
        for (int j = 0; j < 6; ++j) x[j] = rp[j][off];
        #pragma unroll
        for (int j = 0; j < 6; ++j) ss[j] += dot4(x[j], x[j]);
        #pragma unroll
        for (int j = 0; j < 4; ++j) {
            d1[j] += dot4(x[j], x[j + 1]);
            d2[j] += dot4(x[j], x[j + 2]);
        }
    }
    #pragma unroll
    for (int j = 0; j < 6; ++j) ss[j] = wave_sum(ss[j]);
    #pragma unroll
    for (int j = 0; j < 4; ++j) { d1[j] = wave_sum(d1[j]); d2[j] = wave_sum(d2[j]); }

    // features for 8 edges: e<4 -> m1[t0+e]; e>=4 -> m2[t0+e-4]
    float dist[8], cosv[8];
    #pragma unroll
    for (int e = 0; e < 4; ++e) {
        float si = ss[e], sj = ss[e + 1], d = d1[e];
        dist[e] = sqrtf(fmaxf(si + sj - 2.f * d, 0.f));
        cosv[e] = d / (fmaxf(sqrtf(si), 1e-6f) * fmaxf(sqrtf(sj), 1e-6f));
        float sk = ss[e + 2], dd = d2[e];
        dist[4 + e] = sqrtf(fmaxf(si + sk - 2.f * dd, 0.f));
        cosv[4 + e] = dd / (fmaxf(sqrtf(si), 1e-6f) * fmaxf(sqrtf(sk), 1e-6f));
    }
    float acc[8] = {0.f, 0.f, 0.f, 0.f, 0.f, 0.f, 0.f, 0.f};
    #pragma unroll
    for (int k = 0; k < 6; ++k) {
        int u = k * 64 + lane;
        float wd = w1[u], wc = w1[INNER_ + u], bb = b1[u], wv = w2[u];
        #pragma unroll
        for (int e = 0; e < 8; ++e) {
            float z = fmaf(dist[e], wd, fmaf(cosv[e], wc, bb));
            float g = 0.5f * z * (1.f + erff(z * 0.70710678118654752f)); // exact gelu
            acc[e] = fmaf(g, wv, acc[e]);
        }
    }
    #pragma unroll
    for (int e = 0; e < 8; ++e) acc[e] = wave_sum(acc[e]);

    if (lane == 0) {
        float b2v = b2[0];
        float* mB = mu + (size_t)b * EDGES_;
        #pragma unroll
        for (int e = 0; e < 4; ++e) {
            int tt = t0 + e;
            float a1 = acc[e] + b2v;
            float sp1 = fmaxf(a1, 0.f) + log1pf(expf(-fabsf(a1)));
            float m1 = fminf(sp1 + 1e-5f, MU_MAX_);
            if (tt < L_ - 1) mB[tt] = m1;
            float a2 = acc[4 + e] + b2v;
            float sp2 = fmaxf(a2, 0.f) + log1pf(expf(-fabsf(a2)));
            float m2 = fminf(sp2 + 1e-5f, MU_MAX_);
            if (tt < L_ - 2) mB[(L_ - 1) + tt] = m2;
        }
    }
}

// ---------------- per-row 7-point stencil coefficients from mu halo ----------
static __device__ __forceinline__ void row_coeffs(
    int p, const float* __restrict__ mp, float coef, float C[7], float e[3])
{
    float m1a[8];
    #pragma unroll
    for (int j = 0; j < 8; ++j) {
        int u = p - 4 + j;
        m1a[j] = (u >= 0 && u < L_ - 1) ? mp[u] : 0.f;
    }
    float m2a[9];
    #pragma unroll
    for (int j = 0; j < 9; ++j) {
        int u = p - 5 + j;
        m2a[j] = (u >= 0 && u < L_ - 2) ? mp[(L_ - 1) + u] : 0.f;
    }
    float invv[7];
    #pragma unroll
    for (int d = 0; d < 7; ++d) {
        int u = p - 3 + d;
        if (u < 0 || u >= L_) { invv[d] = 0.f; }
        else {
            float deg = m1a[d + 1] + m1a[d] + m2a[d + 2] + m2a[d];
            invv[d] = 1.f / sqrtf(fmaxf(deg, 1e-6f));
        }
    }
    float gwv[3];
    gwv[0] = (p == 0) ? 0.f : LAM_;
    gwv[2] = (p == L_ - 1) ? 0.f : LAM_;
    gwv[1] = 1.f - 2.f * LAM_ + ((p == 0 || p == L_ - 1) ? LAM_ : 0.f);
    #pragma unroll
    for (int d = 0; d < 7; ++d) C[d] = 0.f;
    #pragma unroll
    for (int i = 0; i < 3; ++i) {            // s1 row k = p-1+i
        float g = gwv[i];
        float wm2 = m2a[i + 2] * invv[i + 2] * invv[i];
        float wm1 = m1a[i + 2] * invv[i + 2] * invv[i + 1];
        float wp1 = m1a[i + 3] * invv[i + 2] * invv[i + 3];
        float wp2 = m2a[i + 4] * invv[i + 2] * invv[i + 4];
        float wsum = wm2 + wm1 + wp1 + wp2;
        C[i]     = fmaf(g * coef, wm2, C[i]);
        C[i + 1] = fmaf(g * coef, wm1, C[i + 1]);
        C[i + 2] = fmaf(g, fmaf(-coef, wsum, 1.f), C[i + 2]);
        C[i + 3] = fmaf(g * coef, wp1, C[i + 3]);
        C[i + 4] = fmaf(g * coef, wp2, C[i + 4]);
        e[i] = g * coef;
    }
}

// ---------------- residual + LayerNorm of one row held in registers ----------
static __device__ __forceinline__ void ln_store(
    const float4 rr[3], const float* __restrict__ hrow,
    const float* __restrict__ gamma, const float* __restrict__ beta,
    float* __restrict__ orow, int lane)
{
    float sum = 0.f, sq = 0.f;
    float4 v[3];
    #pragma unroll
    for (int ch = 0; ch < 3; ++ch) {
        int off = ch * 64 + lane;
        float4 h = ((const float4*)hrow)[off];
        float4 x = rr[ch];
        x.x += h.x; x.y += h.y; x.z += h.z; x.w += h.w;
        v[ch] = x;
        sum += x.x + x.y + x.z + x.w;
        sq  += x.x * x.x + x.y * x.y + x.z * x.z + x.w * x.w;
    }
    sum = wave_sum(sum); sq = wave_sum(sq);
    float mean = sum * (1.f / H_);
    float var  = sq * (1.f / H_) - mean * mean;
    float rs = 1.f / sqrtf(var + 1e-5f);
    #pragma unroll
    for (int ch = 0; ch < 3; ++ch) {
        int off = ch * 64 + lane;
        float4 g4 = ((const float4*)gamma)[off];
        float4 b4 = ((const float4*)beta)[off];
        float4 o;
        o.x = (v[ch].x - mean) * rs * g4.x + b4.x;
        o.y = (v[ch].y - mean) * rs * g4.y + b4.y;
        o.z = (v[ch].z - mean) * rs * g4.z + b4.z;
        o.w = (v[ch].w - mean) * rs * g4.w + b4.w;
        ((float4*)orow)[off] = o;
    }
}

// ---------------- paired update: each wave computes rows t0, t0+1 -------------
template <int LN>
__global__ __launch_bounds__(256) void upd_pair_kernel(
    const float* __restrict__ src, const float* __restrict__ q,
    const float* __restrict__ mu, float* __restrict__ dst,
    const float* __restrict__ hidden, const float* __restrict__ gamma,
    const float* __restrict__ beta, float* __restrict__ lnout, float coef)
{
    int blk = blockIdx.x;
    int chunk = (blk & 7) * ((B_ * L_ / 8) / 8) + (blk >> 3);   // bijective
    int b = chunk >> 8;                      // 256 blocks per batch
    int p0 = (chunk & 255) * 8;
    int w = threadIdx.x >> 6, lane = threadIdx.x & 63;
    int t0 = p0 + 2 * w;                     // rows t0, t0+1 (always valid)

    const float* mp = mu + (size_t)b * EDGES_;
    const float* sB = src + (size_t)b * L_ * H_;
    const float* qB = q + (size_t)b * L_ * H_;

    float CA[7], eA[3], CB[7], eB[3];
    row_coeffs(t0, mp, coef, CA, eA);
    row_coeffs(t0 + 1, mp, coef, CB, eB);

    const float* sp[8];
    #pragma unroll
    for (int u = 0; u < 8; ++u) {
        int g = min(max(t0 - 3 + u, 0), L_ - 1);
        sp[u] = sB + (size_t)g * H_;
    }
    const float* qp[4];
    #pragma unroll
    for (int u = 0; u < 4; ++u) {
        int g = min(max(t0 - 1 + u, 0), L_ - 1);
        qp[u] = qB + (size_t)g * H_;
    }

    float* dA = dst + ((size_t)b * L_ + t0) * H_;
    float4 keepA[3], keepB[3];
    #pragma unroll
    for (int ch = 0; ch < 3; ++ch) {
        int off = ch * 64 + lane;
        float4 S[8], Q[4];
        #pragma unroll
        for (int u = 0; u < 8; ++u) S[u] = ((const float4*)sp[u])[off];
        #pragma unroll
        for (int u = 0; u < 4; ++u) Q[u] = ((const float4*)qp[u])[off];
        float4 a = {0.f, 0.f, 0.f, 0.f}, c2 = {0.f, 0.f, 0.f, 0.f};
        #pragma unroll
        for (int d = 0; d < 7; ++d) { fma4(a, CA[d], S[d]); fma4(c2, CB[d], S[d + 1]); }
        #pragma unroll
        for (int i = 0; i < 3; ++i) { fma4(a, eA[i], Q[i]); fma4(c2, eB[i], Q[i + 1]); }
        ((float4*)dA)[off] = a;
        ((float4*)(dA + H_))[off] = c2;
        if (LN) { keepA[ch] = a; keepB[ch] = c2; }
    }

    if (LN) {
        size_t rowA = (size_t)b * L_ + t0;
        ln_store(keepA, hidden + rowA * H_, gamma, beta, lnout + rowA * H_, lane);
        ln_store(keepB, hidden + (rowA + 1) * H_, gamma, beta,
                 lnout + (rowA + 1) * H_, lane);
    }
}

// ---------------- energy ----------------
__global__ void zero_energy_kernel(float* __restrict__ e) {
    if (threadIdx.x < B_) e[threadIdx.x] = 0.f;
}

#define EPW 16
__global__ __launch_bounds__(256) void energy_kernel(
    const float* __restrict__ state, const int* __restrict__ ei, const int* __restrict__ ej,
    const float* __restrict__ mu, float* __restrict__ energy, int E)
{
    __shared__ float red[4];
    int wib = threadIdx.x >> 6;
    int lane = threadIdx.x & 63;
    int nchunk = (E + 63) / 64;
    int b = blockIdx.x / nchunk;
    int chunk = blockIdx.x - b * nchunk;
    int e0 = chunk * 64 + wib * EPW;
    const float* base = state + (size_t)b * L_ * H_;
    const float* muB = mu + (size_t)b * E;
    float part = 0.f;
    for (int k = 0; k < EPW; ++k) {
        int e = e0 + k;
        if (e >= E) break;
        int i = ei[e], j = ej[e];
        const float4* ri = (const float4*)(base + (size_t)i * H_);
        const float4* rj = (const float4*)(base + (size_t)j * H_);
        float s = 0.f;
        #pragma unroll
        for (int it = 0; it < 3; ++it) {
            float4 xi = ri[it * 64 + lane], xj = rj[it * 64 + lane];
            float dx = xi.x - xj.x, dy = xi.y - xj.y, dz = xi.z - xj.z, dw = xi.w - xj.w;
            s += dx*dx + dy*dy + dz*dz + dw*dw;
        }
        s = wave_sum(s);
        part += muB[e] * s;
    }
    if (lane == 0) red[wib] = part;
    __syncthreads();
    if (threadIdx.x == 0)
        atomicAdd(energy + b, 0.5f * (red[0] + red[1] + red[2] + red[3]));
}

extern "C" void kernel_launch(void* const* d_in, const int* in_sizes, int n_in,
                              void* d_out, int out_size, void* d_ws, size_t ws_size,
                              hipStream_t stream)
{
    const float* hidden = (const float*)d_in[0];
    // d_in[1] attention_mask: all ones, unused by the reference math
    const float* w1 = (const float*)d_in[2];
    const float* b1 = (const float*)d_in[3];
    const float* w2 = (const float*)d_in[4];
    const float* b2 = (const float*)d_in[5];
    const float* wq = (const float*)d_in[6];
    const float* bq = (const float*)d_in[7];
    const float* gamma = (const float*)d_in[8];
    const float* beta  = (const float*)d_in[9];
    const int* ei = (const int*)d_in[10];
    const int* ej = (const int*)d_in[11];
    int E = in_sizes[10];   // 2L-3 = 4093

    const size_t BLH = (size_t)B_ * L_ * H_;
    float* out = (float*)d_out;
    float* energy = out + BLH;   // outputs concatenated: out (B,L,H) then energy (B,)

    // workspace: q | bufA | bufB | mu | wt
    float* q    = (float*)d_ws;
    float* bufA = q + BLH;
    float* bufB = bufA + BLH;
    float* mu   = bufB + BLH;
    ushort* wt  = (ushort*)(mu + (size_t)B_ * EDGES_);

    conv_wqt_kernel<<<dim3(H_ / 64, H_ / 64), 256, 0, stream>>>(wq, wt);
    gemm_q_kernel<<<(B_ * L_ / GBM) * (H_ / GBN), 256, 0, stream>>>(hidden, wt, bq, q);
    zero_energy_kernel<<<1, 64, 0, stream>>>(energy);

    const int NBQ = B_ * L_ / 16;    // mu grid: one wave per 4 rows
    const int NBP = B_ * L_ / 8;     // update grid: one wave per 2 rows
    float coef = 0.1f;               // ETA * 0.9^step

    // step 0: hidden -> bufA
    mu_quad_kernel<<<NBQ, 256, 0, stream>>>(hidden, w1, b1, w2, b2, mu);
    upd_pair_kernel<0><<<NBP, 256, 0, stream>>>(hidden, q, mu, bufA,
        hidden, gamma, beta, nullptr, coef);
    coef *= 0.9f;
    // step 1: bufA -> bufB
    mu_quad_kernel<<<NBQ, 256, 0, stream>>>(bufA, w1, b1, w2, b2, mu);
    upd_pair_kernel<0><<<NBP, 256, 0, stream>>>(bufA, q, mu, bufB,
        hidden, gamma, beta, nullptr, coef);
    coef *= 0.9f;
    // step 2: bufB -> bufA
    mu_quad_kernel<<<NBQ, 256, 0, stream>>>(bufB, w1, b1, w2, b2, mu);
    upd_pair_kernel<0><<<NBP, 256, 0, stream>>>(bufB, q, mu, bufA,
        hidden, gamma, beta, nullptr, coef);
    coef *= 0.9f;
    // step 3: bufA -> bufB, fused residual+LN (energy needs mu_3 = mu(bufA))
    mu_quad_kernel<<<NBQ, 256, 0, stream>>>(bufA, w1, b1, w2, b2, mu);
    upd_pair_kernel<1><<<NBP, 256, 0, stream>>>(bufA, q, mu, bufB,
        hidden, gamma, beta, out, coef);

    int nchunk = (E + 63) / 64;
    energy_kernel<<<B_ * nchunk, 256, 0, stream>>>(bufB, ei, ej, mu, energy, E);
}

// Round 6
// 777.107 us; speedup vs baseline: 1.0924x; 1.0924x over previous
//
#include <hip/hip_runtime.h>
#include <hip/hip_bf16.h>
#include <math.h>

#define B_ 16
#define L_ 2048
#define H_ 768
#define INNER_ 384
#define MU_MAX_ 10.0f
#define LAM_ 0.1f
#define EDGES_ (2 * L_ - 3)   // 4093

typedef short v8bf __attribute__((ext_vector_type(8)));   // 8 bf16 (4 VGPRs)
typedef float v4f  __attribute__((ext_vector_type(4)));   // MFMA accumulator

static __device__ __forceinline__ float wave_sum(float v) {
    #pragma unroll
    for (int o = 32; o > 0; o >>= 1) v += __shfl_xor(v, o, 64);
    return v;
}

static __device__ __forceinline__ float dot4(const float4& a, const float4& b) {
    return a.x * b.x + a.y * b.y + a.z * b.z + a.w * b.w;
}

static __device__ __forceinline__ void fma4(float4& a, float c, float4 x) {
    a.x = fmaf(c, x.x, a.x); a.y = fmaf(c, x.y, a.y);
    a.z = fmaf(c, x.z, a.z); a.w = fmaf(c, x.w, a.w);
}

// round-to-nearest-even fp32 -> bf16 (matches numpy/JAX casting)
static __device__ __forceinline__ ushort f2bf(float x) {
    unsigned u = __float_as_uint(x);
    u += 0x7fffu + ((u >> 16) & 1u);
    return (ushort)(u >> 16);
}

// ---------------- convert hidden fp32 -> bf16 (8 elems/thread) ----------------
__global__ __launch_bounds__(256) void conv_bf16_kernel(
    const float* __restrict__ in, ushort* __restrict__ out, int n8)
{
    int t = blockIdx.x * 256 + threadIdx.x;
    if (t >= n8) return;
    float4 a = ((const float4*)in)[2 * t];
    float4 b = ((const float4*)in)[2 * t + 1];
    ushort r[8] = { f2bf(a.x), f2bf(a.y), f2bf(a.z), f2bf(a.w),
                    f2bf(b.x), f2bf(b.y), f2bf(b.z), f2bf(b.w) };
    ((v8bf*)out)[t] = *(v8bf*)r;
}

// ---------------- convert + transpose wq (K x N fp32) -> wt (N x K bf16) -------
__global__ __launch_bounds__(256) void conv_wqt_kernel(
    const float* __restrict__ wq, ushort* __restrict__ wt)
{
    __shared__ float tile[64][65];
    int k0 = blockIdx.x * 64, n0 = blockIdx.y * 64;
    int t = threadIdx.x;
    #pragma unroll
    for (int it = 0; it < 16; ++it) {
        int lin = t + it * 256;
        int r = lin >> 6, c = lin & 63;         // r: k, c: n  (coalesced read)
        tile[r][c] = wq[(size_t)(k0 + r) * H_ + n0 + c];
    }
    __syncthreads();
    #pragma unroll
    for (int it = 0; it < 16; ++it) {
        int lin = t + it * 256;
        int r = lin >> 6, c = lin & 63;         // r: n, c: k  (coalesced write)
        wt[(size_t)(n0 + r) * H_ + k0 + c] = f2bf(tile[c][r]);
    }
}

// ---------------- MFMA GEMM: q = A(bf16) @ wt^T + bq ----------------
// XCD-co-located 1D grid (proven: FETCH 302->64 MB): idx&7 = XCD; the 6
// n-blocks of one A m-tile run on the same XCD back-to-back, so the A panel
// is HBM-fetched once. Both operands LDS-staged (padded stride -> conflict-
// free ds_read_b128) with register double-buffer prefetch so global/L2
// latency hides under the MFMA phase.
#define GBM 128
#define GBN 128
#define GBK 64
#define LSTR 72   // padded LDS row stride in bf16 (2-way bank alias = free)

__global__ __launch_bounds__(256) void gemm_q_kernel(
    const ushort* __restrict__ A, const ushort* __restrict__ Wt,
    const float* __restrict__ bias, float* __restrict__ C)
{
    __shared__ ushort As[GBM * LSTR];
    __shared__ ushort Bs[GBN * LSTR];
    const int K = H_, N = H_;
    int idx = blockIdx.x;
    int c = idx & 7, rest = idx >> 3;            // rest 0..191 per XCD
    int n0 = (rest % 6) * GBN;
    int m0 = ((rest / 6) * 8 + c) * GBM;         // m-tile pinned to XCD c
    int t = threadIdx.x;
    int lane = t & 63, w = t >> 6;
    int wm = (w & 1) * 64, wn = (w >> 1) * 64;
    int row16 = lane & 15, quad = lane >> 4;

    v4f acc[4][4];
    #pragma unroll
    for (int i = 0; i < 4; ++i)
        #pragma unroll
        for (int j = 0; j < 4; ++j)
            acc[i][j] = (v4f){0.f, 0.f, 0.f, 0.f};

    v8bf pfA[4], pfB[4];
    #pragma unroll
    for (int it = 0; it < 4; ++it) {
        int lin = t + it * 256;
        int r = lin >> 3, s = lin & 7;
        pfA[it] = *(const v8bf*)(A  + (size_t)(m0 + r) * K + s * 8);
        pfB[it] = *(const v8bf*)(Wt + (size_t)(n0 + r) * K + s * 8);
    }

    for (int kt = 0; kt < 12; ++kt) {
        int k0 = kt * GBK;
        #pragma unroll
        for (int it = 0; it < 4; ++it) {
            int lin = t + it * 256;
            int r = lin >> 3, s = lin & 7;
            *(v8bf*)&As[r * LSTR + s * 8] = pfA[it];
            *(v8bf*)&Bs[r * LSTR + s * 8] = pfB[it];
        }
        if (kt < 11) {
            int kn = k0 + GBK;
            #pragma unroll
            for (int it = 0; it < 4; ++it) {
                int lin = t + it * 256;
                int r = lin >> 3, s = lin & 7;
                pfA[it] = *(const v8bf*)(A  + (size_t)(m0 + r) * K + kn + s * 8);
                pfB[it] = *(const v8bf*)(Wt + (size_t)(n0 + r) * K + kn + s * 8);
            }
        }
        __syncthreads();
        #pragma unroll
        for (int h = 0; h < 2; ++h) {
            v8bf af[4], bfv[4];
            #pragma unroll
            for (int i = 0; i < 4; ++i)
                af[i] = *(v8bf*)&As[(wm + i * 16 + row16) * LSTR + h * 32 + quad * 8];
            #pragma unroll
            for (int j = 0; j < 4; ++j)
                bfv[j] = *(v8bf*)&Bs[(wn + j * 16 + row16) * LSTR + h * 32 + quad * 8];
            #pragma unroll
            for (int i = 0; i < 4; ++i)
                #pragma unroll
                for (int j = 0; j < 4; ++j)
                    acc[i][j] = __builtin_amdgcn_mfma_f32_16x16x32_bf16(
                        af[i], bfv[j], acc[i][j], 0, 0, 0);
        }
        __syncthreads();
    }
    #pragma unroll
    for (int j = 0; j < 4; ++j) {
        int ncol = n0 + wn + j * 16 + row16;
        float bqv = bias[ncol];
        #pragma unroll
        for (int i = 0; i < 4; ++i) {
            int mrow = m0 + wm + i * 16 + quad * 4;
            #pragma unroll
            for (int r = 0; r < 4; ++r)
                C[(size_t)(mrow + r) * N + ncol] = acc[i][j][r] + bqv;
        }
    }
}

// ---------------- MLP: (dist,cos) -> mu, lanes parallel over INNER -------------
static __device__ __forceinline__ float mu_mlp2(
    float si, float sj, float dotij,
    const float* w1d, const float* w1c, const float* b1v, const float* w2v,
    float b2v)
{
    float dist = sqrtf(fmaxf(si + sj - 2.f * dotij, 0.f));
    float cosv = dotij / (fmaxf(sqrtf(si), 1e-6f) * fmaxf(sqrtf(sj), 1e-6f));
    float acc = 0.f;
    #pragma unroll
    for (int k = 0; k < 6; ++k) {
        float z = fmaf(dist, w1d[k], fmaf(cosv, w1c[k], b1v[k]));
        float g = 0.5f * z * (1.f + erff(z * 0.70710678118654752f)); // exact gelu
        acc = fmaf(g, w2v[k], acc);
    }
    acc = wave_sum(acc) + b2v;
    float sp = fmaxf(acc, 0.f) + log1pf(expf(-fabsf(acc)));  // stable softplus
    return fminf(sp + 1e-5f, MU_MAX_);
}

// ---------------- mu: one wave per row-pair (t0, t0+1), 4 row loads -----------
__global__ __launch_bounds__(256) void mu_pair_kernel(
    const float* __restrict__ src,
    const float* __restrict__ w1, const float* __restrict__ b1,
    const float* __restrict__ w2, const float* __restrict__ b2,
    float* __restrict__ mu)
{
    int blk = blockIdx.x;
    int chunk = (blk & 7) * ((B_ * L_ / 8) / 8) + (blk >> 3);  // XCD-contiguous
    int b = chunk >> 8;                       // 256 blocks per batch
    int p0 = (chunk & 255) * 8;
    int w = threadIdx.x >> 6, lane = threadIdx.x & 63;
    int t0 = p0 + 2 * w;                      // even, 0..L-2

    const float* sB = src + (size_t)b * L_ * H_;
    int r2 = min(t0 + 2, L_ - 1), r3 = min(t0 + 3, L_ - 1);
    const float4* x0p = (const float4*)(sB + (size_t)t0 * H_);
    const float4* x1p = (const float4*)(sB + (size_t)(t0 + 1) * H_);
    const float4* x2p = (const float4*)(sB + (size_t)r2 * H_);
    const float4* x3p = (const float4*)(sB + (size_t)r3 * H_);

    float ss0 = 0.f, ss1 = 0.f, ss2 = 0.f, ss3 = 0.f;
    float d1a = 0.f, d1b = 0.f, d2a = 0.f, d2b = 0.f;
    #pragma unroll
    for (int ch = 0; ch < 3; ++ch) {
        int off = ch * 64 + lane;
        float4 x0 = x0p[off], x1 = x1p[off], x2 = x2p[off], x3 = x3p[off];
        ss0 += dot4(x0, x0); ss1 += dot4(x1, x1);
        ss2 += dot4(x2, x2); ss3 += dot4(x3, x3);
        d1a += dot4(x0, x1); d1b += dot4(x1, x2);
        d2a += dot4(x0, x2); d2b += dot4(x1, x3);
    }
    ss0 = wave_sum(ss0); ss1 = wave_sum(ss1); ss2 = wave_sum(ss2);
    d1a = wave_sum(d1a); d1b = wave_sum(d1b); d2a = wave_sum(d2a);

    float w1d[6], w1c[6], b1v[6], w2v[6];
    #pragma unroll
    for (int k = 0; k < 6; ++k) {
        int u = k * 64 + lane;
        w1d[k] = w1[u]; w1c[k] = w1[INNER_ + u]; b1v[k] = b1[u]; w2v[k] = w2[u];
    }
    float b2v = b2[0];
    float* mB = mu + (size_t)b * EDGES_;

    // edges from row t0 (t0 <= L-2 always, so m1[t0] always valid)
    float m1a = mu_mlp2(ss0, ss1, d1a, w1d, w1c, b1v, w2v, b2v);
    if (lane == 0) mB[t0] = m1a;
    if (t0 < L_ - 2) {
        float m2a_ = mu_mlp2(ss0, ss2, d2a, w1d, w1c, b1v, w2v, b2v);
        if (lane == 0) mB[(L_ - 1) + t0] = m2a_;
        // edges from row t0+1
        float m1b = mu_mlp2(ss1, ss2, d1b, w1d, w1c, b1v, w2v, b2v);
        if (lane == 0) mB[t0 + 1] = m1b;
        if (t0 + 1 < L_ - 2) {
            ss3 = wave_sum(ss3); d2b = wave_sum(d2b);
            float m2b = mu_mlp2(ss1, ss3, d2b, w1d, w1c, b1v, w2v, b2v);
            if (lane == 0) mB[(L_ - 1) + t0 + 1] = m2b;
        }
    }
}

// ---------------- per-row 7-point stencil coefficients from mu halo ----------
static __device__ __forceinline__ void row_coeffs(
    int p, const float* __restrict__ mp, float coef, float C[7], float e[3])
{
    float m1a[8];
    #pragma unroll
    for (int j = 0; j < 8; ++j) {
        int u = p - 4 + j;
        m1a[j] = (u >= 0 && u < L_ - 1) ? mp[u] : 0.f;
    }
    float m2a[9];
    #pragma unroll
    for (int j = 0; j < 9; ++j) {
        int u = p - 5 + j;
        m2a[j] = (u >= 0 && u < L_ - 2) ? mp[(L_ - 1) + u] : 0.f;
    }
    float invv[7];
    #pragma unroll
    for (int d = 0; d < 7; ++d) {
        int u = p - 3 + d;
        if (u < 0 || u >= L_) { invv[d] = 0.f; }
        else {
            float deg = m1a[d + 1] + m1a[d] + m2a[d + 2] + m2a[d];
            invv[d] = 1.f / sqrtf(fmaxf(deg, 1e-6f));
        }
    }
    float gwv[3];
    gwv[0] = (p == 0) ? 0.f : LAM_;
    gwv[2] = (p == L_ - 1) ? 0.f : LAM_;
    gwv[1] = 1.f - 2.f * LAM_ + ((p == 0 || p == L_ - 1) ? LAM_ : 0.f);
    #pragma unroll
    for (int d = 0; d < 7; ++d) C[d] = 0.f;
    #pragma unroll
    for (int i = 0; i < 3; ++i) {            // s1 row k = p-1+i
        float g = gwv[i];
        float wm2 = m2a[i + 2] * invv[i + 2] * invv[i];
        float wm1 = m1a[i + 2] * invv[i + 2] * invv[i + 1];
        float wp1 = m1a[i + 3] * invv[i + 2] * invv[i + 3];
        float wp2 = m2a[i + 4] * invv[i + 2] * invv[i + 4];
        float wsum = wm2 + wm1 + wp1 + wp2;
        C[i]     = fmaf(g * coef, wm2, C[i]);
        C[i + 1] = fmaf(g * coef, wm1, C[i + 1]);
        C[i + 2] = fmaf(g, fmaf(-coef, wsum, 1.f), C[i + 2]);
        C[i + 3] = fmaf(g * coef, wp1, C[i + 3]);
        C[i + 4] = fmaf(g * coef, wp2, C[i + 4]);
        e[i] = g * coef;
    }
}

// ---------------- residual + LayerNorm of one row held in registers ----------
static __device__ __forceinline__ void ln_store(
    const float4 rr[3], const float* __restrict__ hrow,
    const float* __restrict__ gamma, const float* __restrict__ beta,
    float* __restrict__ orow, int lane)
{
    float sum = 0.f, sq = 0.f;
    float4 v[3];
    #pragma unroll
    for (int ch = 0; ch < 3; ++ch) {
        int off = ch * 64 + lane;
        float4 h = ((const float4*)hrow)[off];
        float4 x = rr[ch];
        x.x += h.x; x.y += h.y; x.z += h.z; x.w += h.w;
        v[ch] = x;
        sum += x.x + x.y + x.z + x.w;
        sq  += x.x * x.x + x.y * x.y + x.z * x.z + x.w * x.w;
    }
    sum = wave_sum(sum); sq = wave_sum(sq);
    float mean = sum * (1.f / H_);
    float var  = sq * (1.f / H_) - mean * mean;
    float rs = 1.f / sqrtf(var + 1e-5f);
    #pragma unroll
    for (int ch = 0; ch < 3; ++ch) {
        int off = ch * 64 + lane;
        float4 g4 = ((const float4*)gamma)[off];
        float4 b4 = ((const float4*)beta)[off];
        float4 o;
        o.x = (v[ch].x - mean) * rs * g4.x + b4.x;
        o.y = (v[ch].y - mean) * rs * g4.y + b4.y;
        o.z = (v[ch].z - mean) * rs * g4.z + b4.z;
        o.w = (v[ch].w - mean) * rs * g4.w + b4.w;
        ((float4*)orow)[off] = o;
    }
}

// ---------------- paired update: each wave computes rows t0, t0+1 -------------
template <int LN>
__global__ __launch_bounds__(256) void upd_pair_kernel(
    const float* __restrict__ src, const float* __restrict__ q,
    const float* __restrict__ mu, float* __restrict__ dst,
    const float* __restrict__ hidden, const float* __restrict__ gamma,
    const float* __restrict__ beta, float* __restrict__ lnout, float coef)
{
    int blk = blockIdx.x;
    int chunk = (blk & 7) * ((B_ * L_ / 8) / 8) + (blk >> 3);   // bijective
    int b = chunk >> 8;                      // 256 blocks per batch
    int p0 = (chunk & 255) * 8;
    int w = threadIdx.x >> 6, lane = threadIdx.x & 63;
    int t0 = p0 + 2 * w;                     // rows t0, t0+1 (always valid)

    const float* mp = mu + (size_t)b * EDGES_;
    const float* sB = src + (size_t)b * L_ * H_;
    const float* qB = q + (size_t)b * L_ * H_;

    float CA[7], eA[3], CB[7], eB[3];
    row_coeffs(t0, mp, coef, CA, eA);
    row_coeffs(t0 + 1, mp, coef, CB, eB);

    const float* sp[8];
    #pragma unroll
    for (int u = 0; u < 8; ++u) {
        int g = min(max(t0 - 3 + u, 0), L_ - 1);
        sp[u] = sB + (size_t)g * H_;
    }
    const float* qp[4];
    #pragma unroll
    for (int u = 0; u < 4; ++u) {
        int g = min(max(t0 - 1 + u, 0), L_ - 1);
        qp[u] = qB + (size_t)g * H_;
    }

    float* dA = dst + ((size_t)b * L_ + t0) * H_;
    float4 keepA[3], keepB[3];
    #pragma unroll
    for (int ch = 0; ch < 3; ++ch) {
        int off = ch * 64 + lane;
        float4 S[8], Q[4];
        #pragma unroll
        for (int u = 0; u < 8; ++u) S[u] = ((const float4*)sp[u])[off];
        #pragma unroll
        for (int u = 0; u < 4; ++u) Q[u] = ((const float4*)qp[u])[off];
        float4 a = {0.f, 0.f, 0.f, 0.f}, c2 = {0.f, 0.f, 0.f, 0.f};
        #pragma unroll
        for (int d = 0; d < 7; ++d) { fma4(a, CA[d], S[d]); fma4(c2, CB[d], S[d + 1]); }
        #pragma unroll
        for (int i = 0; i < 3; ++i) { fma4(a, eA[i], Q[i]); fma4(c2, eB[i], Q[i + 1]); }
        ((float4*)dA)[off] = a;
        ((float4*)(dA + H_))[off] = c2;
        if (LN) { keepA[ch] = a; keepB[ch] = c2; }
    }

    if (LN) {
        size_t rowA = (size_t)b * L_ + t0;
        ln_store(keepA, hidden + rowA * H_, gamma, beta, lnout + rowA * H_, lane);
        ln_store(keepB, hidden + (rowA + 1) * H_, gamma, beta,
                 lnout + (rowA + 1) * H_, lane);
    }
}

// ---------------- energy ----------------
__global__ void zero_energy_kernel(float* __restrict__ e) {
    if (threadIdx.x < B_) e[threadIdx.x] = 0.f;
}

#define EPW 16
__global__ __launch_bounds__(256) void energy_kernel(
    const float* __restrict__ state, const int* __restrict__ ei, const int* __restrict__ ej,
    const float* __restrict__ mu, float* __restrict__ energy, int E)
{
    __shared__ float red[4];
    int wib = threadIdx.x >> 6;
    int lane = threadIdx.x & 63;
    int nchunk = (E + 63) / 64;
    int b = blockIdx.x / nchunk;
    int chunk = blockIdx.x - b * nchunk;
    int e0 = chunk * 64 + wib * EPW;
    const float* base = state + (size_t)b * L_ * H_;
    const float* muB = mu + (size_t)b * E;
    float part = 0.f;
    for (int k = 0; k < EPW; ++k) {
        int e = e0 + k;
        if (e >= E) break;
        int i = ei[e], j = ej[e];
        const float4* ri = (const float4*)(base + (size_t)i * H_);
        const float4* rj = (const float4*)(base + (size_t)j * H_);
        float s = 0.f;
        #pragma unroll
        for (int it = 0; it < 3; ++it) {
            float4 xi = ri[it * 64 + lane], xj = rj[it * 64 + lane];
            float dx = xi.x - xj.x, dy = xi.y - xj.y, dz = xi.z - xj.z, dw = xi.w - xj.w;
            s += dx*dx + dy*dy + dz*dz + dw*dw;
        }
        s = wave_sum(s);
        part += muB[e] * s;
    }
    if (lane == 0) red[wib] = part;
    __syncthreads();
    if (threadIdx.x == 0)
        atomicAdd(energy + b, 0.5f * (red[0] + red[1] + red[2] + red[3]));
}

extern "C" void kernel_launch(void* const* d_in, const int* in_sizes, int n_in,
                              void* d_out, int out_size, void* d_ws, size_t ws_size,
                              hipStream_t stream)
{
    const float* hidden = (const float*)d_in[0];
    // d_in[1] attention_mask: all ones, unused by the reference math
    const float* w1 = (const float*)d_in[2];
    const float* b1 = (const float*)d_in[3];
    const float* w2 = (const float*)d_in[4];
    const float* b2 = (const float*)d_in[5];
    const float* wq = (const float*)d_in[6];
    const float* bq = (const float*)d_in[7];
    const float* gamma = (const float*)d_in[8];
    const float* beta  = (const float*)d_in[9];
    const int* ei = (const int*)d_in[10];
    const int* ej = (const int*)d_in[11];
    int E = in_sizes[10];   // 2L-3 = 4093

    const size_t BLH = (size_t)B_ * L_ * H_;
    float* out = (float*)d_out;
    float* energy = out + BLH;   // outputs concatenated: out (B,L,H) then energy (B,)

    // workspace: q | bufA | bufB | mu | wt
    float* q    = (float*)d_ws;
    float* bufA = q + BLH;
    float* bufB = bufA + BLH;
    float* mu   = bufB + BLH;
    ushort* Abf = (ushort*)bufA;         // aliases bufA (dead after gemm)
    ushort* wt  = (ushort*)(mu + (size_t)B_ * EDGES_);

    int n8 = (int)(BLH / 8);
    conv_bf16_kernel<<<(n8 + 255) / 256, 256, 0, stream>>>(hidden, Abf, n8);
    conv_wqt_kernel<<<dim3(H_ / 64, H_ / 64), 256, 0, stream>>>(wq, wt);
    gemm_q_kernel<<<(B_ * L_ / GBM) * (H_ / GBN), 256, 0, stream>>>(Abf, wt, bq, q);
    zero_energy_kernel<<<1, 64, 0, stream>>>(energy);

    const int NBP = B_ * L_ / 8;     // paired grids: one wave per 2 rows
    float coef = 0.1f;               // ETA * 0.9^step

    // step 0: hidden -> bufA
    mu_pair_kernel<<<NBP, 256, 0, stream>>>(hidden, w1, b1, w2, b2, mu);
    upd_pair_kernel<0><<<NBP, 256, 0, stream>>>(hidden, q, mu, bufA,
        hidden, gamma, beta, nullptr, coef);
    coef *= 0.9f;
    // step 1: bufA -> bufB
    mu_pair_kernel<<<NBP, 256, 0, stream>>>(bufA, w1, b1, w2, b2, mu);
    upd_pair_kernel<0><<<NBP, 256, 0, stream>>>(bufA, q, mu, bufB,
        hidden, gamma, beta, nullptr, coef);
    coef *= 0.9f;
    // step 2: bufB -> bufA
    mu_pair_kernel<<<NBP, 256, 0, stream>>>(bufB, w1, b1, w2, b2, mu);
    upd_pair_kernel<0><<<NBP, 256, 0, stream>>>(bufB, q, mu, bufA,
        hidden, gamma, beta, nullptr, coef);
    coef *= 0.9f;
    // step 3: bufA -> bufB, fused residual+LN (energy needs mu_3 = mu(bufA))
    mu_pair_kernel<<<NBP, 256, 0, stream>>>(bufA, w1, b1, w2, b2, mu);
    upd_pair_kernel<1><<<NBP, 256, 0, stream>>>(bufA, q, mu, bufB,
        hidden, gamma, beta, out, coef);

    int nchunk = (E + 63) / 64;
    energy_kernel<<<B_ * nchunk, 256, 0, stream>>>(bufB, ei, ej, mu, energy, E);
}

// Round 7
// 754.610 us; speedup vs baseline: 1.1250x; 1.0298x over previous
//
#include <hip/hip_runtime.h>
#include <hip/hip_bf16.h>
#include <math.h>

#define B_ 16
#define L_ 2048
#define H_ 768
#define INNER_ 384
#define MU_MAX_ 10.0f
#define LAM_ 0.1f
#define EDGES_ (2 * L_ - 3)   // 4093

typedef short v8bf __attribute__((ext_vector_type(8)));   // 8 bf16 (4 VGPRs)
typedef float v4f  __attribute__((ext_vector_type(4)));   // MFMA accumulator

static __device__ __forceinline__ float wave_sum(float v) {
    #pragma unroll
    for (int o = 32; o > 0; o >>= 1) v += __shfl_xor(v, o, 64);
    return v;
}

static __device__ __forceinline__ float dot4(const float4& a, const float4& b) {
    return a.x * b.x + a.y * b.y + a.z * b.z + a.w * b.w;
}

static __device__ __forceinline__ void fma4(float4& a, float c, float4 x) {
    a.x = fmaf(c, x.x, a.x); a.y = fmaf(c, x.y, a.y);
    a.z = fmaf(c, x.z, a.z); a.w = fmaf(c, x.w, a.w);
}

// round-to-nearest-even fp32 -> bf16 (matches numpy/JAX casting)
static __device__ __forceinline__ ushort f2bf(float x) {
    unsigned u = __float_as_uint(x);
    u += 0x7fffu + ((u >> 16) & 1u);
    return (ushort)(u >> 16);
}

// ---------------- convert hidden fp32 -> bf16 (8 elems/thread) ----------------
__global__ __launch_bounds__(256) void conv_bf16_kernel(
    const float* __restrict__ in, ushort* __restrict__ out, int n8)
{
    int t = blockIdx.x * 256 + threadIdx.x;
    if (t >= n8) return;
    float4 a = ((const float4*)in)[2 * t];
    float4 b = ((const float4*)in)[2 * t + 1];
    ushort r[8] = { f2bf(a.x), f2bf(a.y), f2bf(a.z), f2bf(a.w),
                    f2bf(b.x), f2bf(b.y), f2bf(b.z), f2bf(b.w) };
    ((v8bf*)out)[t] = *(v8bf*)r;
}

// ---------------- convert + transpose wq (K x N fp32) -> wt (N x K bf16) -------
__global__ __launch_bounds__(256) void conv_wqt_kernel(
    const float* __restrict__ wq, ushort* __restrict__ wt)
{
    __shared__ float tile[64][65];
    int k0 = blockIdx.x * 64, n0 = blockIdx.y * 64;
    int t = threadIdx.x;
    #pragma unroll
    for (int it = 0; it < 16; ++it) {
        int lin = t + it * 256;
        int r = lin >> 6, c = lin & 63;         // r: k, c: n  (coalesced read)
        tile[r][c] = wq[(size_t)(k0 + r) * H_ + n0 + c];
    }
    __syncthreads();
    #pragma unroll
    for (int it = 0; it < 16; ++it) {
        int lin = t + it * 256;
        int r = lin >> 6, c = lin & 63;         // r: n, c: k  (coalesced write)
        wt[(size_t)(n0 + r) * H_ + k0 + c] = f2bf(tile[c][r]);
    }
}

// ---------------- MFMA GEMM: q = A(bf16) @ wt^T + bq ----------------
// XCD-co-located 1D grid (proven: FETCH 302->64 MB): idx&7 = XCD; the 6
// n-blocks of one A m-tile run on the same XCD back-to-back. Both operands
// LDS-staged with register double-buffer prefetch.
#define GBM 128
#define GBN 128
#define GBK 64
#define LSTR 72   // padded LDS row stride in bf16 (2-way bank alias = free)

__global__ __launch_bounds__(256) void gemm_q_kernel(
    const ushort* __restrict__ A, const ushort* __restrict__ Wt,
    const float* __restrict__ bias, float* __restrict__ C)
{
    __shared__ ushort As[GBM * LSTR];
    __shared__ ushort Bs[GBN * LSTR];
    const int K = H_, N = H_;
    int idx = blockIdx.x;
    int c = idx & 7, rest = idx >> 3;            // rest 0..191 per XCD
    int n0 = (rest % 6) * GBN;
    int m0 = ((rest / 6) * 8 + c) * GBM;         // m-tile pinned to XCD c
    int t = threadIdx.x;
    int lane = t & 63, w = t >> 6;
    int wm = (w & 1) * 64, wn = (w >> 1) * 64;
    int row16 = lane & 15, quad = lane >> 4;

    v4f acc[4][4];
    #pragma unroll
    for (int i = 0; i < 4; ++i)
        #pragma unroll
        for (int j = 0; j < 4; ++j)
            acc[i][j] = (v4f){0.f, 0.f, 0.f, 0.f};

    v8bf pfA[4], pfB[4];
    #pragma unroll
    for (int it = 0; it < 4; ++it) {
        int lin = t + it * 256;
        int r = lin >> 3, s = lin & 7;
        pfA[it] = *(const v8bf*)(A  + (size_t)(m0 + r) * K + s * 8);
        pfB[it] = *(const v8bf*)(Wt + (size_t)(n0 + r) * K + s * 8);
    }

    for (int kt = 0; kt < 12; ++kt) {
        int k0 = kt * GBK;
        #pragma unroll
        for (int it = 0; it < 4; ++it) {
            int lin = t + it * 256;
            int r = lin >> 3, s = lin & 7;
            *(v8bf*)&As[r * LSTR + s * 8] = pfA[it];
            *(v8bf*)&Bs[r * LSTR + s * 8] = pfB[it];
        }
        if (kt < 11) {
            int kn = k0 + GBK;
            #pragma unroll
            for (int it = 0; it < 4; ++it) {
                int lin = t + it * 256;
                int r = lin >> 3, s = lin & 7;
                pfA[it] = *(const v8bf*)(A  + (size_t)(m0 + r) * K + kn + s * 8);
                pfB[it] = *(const v8bf*)(Wt + (size_t)(n0 + r) * K + kn + s * 8);
            }
        }
        __syncthreads();
        #pragma unroll
        for (int h = 0; h < 2; ++h) {
            v8bf af[4], bfv[4];
            #pragma unroll
            for (int i = 0; i < 4; ++i)
                af[i] = *(v8bf*)&As[(wm + i * 16 + row16) * LSTR + h * 32 + quad * 8];
            #pragma unroll
            for (int j = 0; j < 4; ++j)
                bfv[j] = *(v8bf*)&Bs[(wn + j * 16 + row16) * LSTR + h * 32 + quad * 8];
            #pragma unroll
            for (int i = 0; i < 4; ++i)
                #pragma unroll
                for (int j = 0; j < 4; ++j)
                    acc[i][j] = __builtin_amdgcn_mfma_f32_16x16x32_bf16(
                        af[i], bfv[j], acc[i][j], 0, 0, 0);
        }
        __syncthreads();
    }
    #pragma unroll
    for (int j = 0; j < 4; ++j) {
        int ncol = n0 + wn + j * 16 + row16;
        float bqv = bias[ncol];
        #pragma unroll
        for (int i = 0; i < 4; ++i) {
            int mrow = m0 + wm + i * 16 + quad * 4;
            #pragma unroll
            for (int r = 0; r < 4; ++r)
                C[(size_t)(mrow + r) * N + ncol] = acc[i][j][r] + bqv;
        }
    }
}

// ---------------- mu: one wave per row-pair, batched MLPs ---------------------
// Same loads/validity as the proven mu_pair; the 4 MLPs run in ONE 6-iter
// INNER pass with 4 independent accumulators + batched wave_sums (per-edge
// arithmetic order identical: k-ascending fma chain, wave_sum, softplus).
__global__ __launch_bounds__(256) void mu_pair_kernel(
    const float* __restrict__ src,
    const float* __restrict__ w1, const float* __restrict__ b1,
    const float* __restrict__ w2, const float* __restrict__ b2,
    float* __restrict__ mu)
{
    int blk = blockIdx.x;
    int chunk = (blk & 7) * ((B_ * L_ / 8) / 8) + (blk >> 3);  // XCD-contiguous
    int b = chunk >> 8;                       // 256 blocks per batch
    int p0 = (chunk & 255) * 8;
    int w = threadIdx.x >> 6, lane = threadIdx.x & 63;
    int t0 = p0 + 2 * w;                      // even, 0..L-2

    const float* sB = src + (size_t)b * L_ * H_;
    int r2 = min(t0 + 2, L_ - 1), r3 = min(t0 + 3, L_ - 1);
    const float4* x0p = (const float4*)(sB + (size_t)t0 * H_);
    const float4* x1p = (const float4*)(sB + (size_t)(t0 + 1) * H_);
    const float4* x2p = (const float4*)(sB + (size_t)r2 * H_);
    const float4* x3p = (const float4*)(sB + (size_t)r3 * H_);

    float ss0 = 0.f, ss1 = 0.f, ss2 = 0.f, ss3 = 0.f;
    float d1a = 0.f, d1b = 0.f, d2a = 0.f, d2b = 0.f;
    #pragma unroll
    for (int ch = 0; ch < 3; ++ch) {
        int off = ch * 64 + lane;
        float4 x0 = x0p[off], x1 = x1p[off], x2 = x2p[off], x3 = x3p[off];
        ss0 += dot4(x0, x0); ss1 += dot4(x1, x1);
        ss2 += dot4(x2, x2); ss3 += dot4(x3, x3);
        d1a += dot4(x0, x1); d1b += dot4(x1, x2);
        d2a += dot4(x0, x2); d2b += dot4(x1, x3);
    }
    ss0 = wave_sum(ss0); ss1 = wave_sum(ss1); ss2 = wave_sum(ss2); ss3 = wave_sum(ss3);
    d1a = wave_sum(d1a); d1b = wave_sum(d1b); d2a = wave_sum(d2a); d2b = wave_sum(d2b);

    // features: e0=m1[t0](ss0,ss1,d1a)  e1=m2[t0](ss0,ss2,d2a)
    //           e2=m1[t0+1](ss1,ss2,d1b) e3=m2[t0+1](ss1,ss3,d2b)
    float dist[4], cosv[4];
    {
        float si[4] = {ss0, ss0, ss1, ss1};
        float sj[4] = {ss1, ss2, ss2, ss3};
        float dd[4] = {d1a, d2a, d1b, d2b};
        #pragma unroll
        for (int e = 0; e < 4; ++e) {
            dist[e] = sqrtf(fmaxf(si[e] + sj[e] - 2.f * dd[e], 0.f));
            cosv[e] = dd[e] / (fmaxf(sqrtf(si[e]), 1e-6f) * fmaxf(sqrtf(sj[e]), 1e-6f));
        }
    }
    float acc[4] = {0.f, 0.f, 0.f, 0.f};
    #pragma unroll
    for (int k = 0; k < 6; ++k) {
        int u = k * 64 + lane;
        float wd = w1[u], wc = w1[INNER_ + u], bb = b1[u], wv = w2[u];
        #pragma unroll
        for (int e = 0; e < 4; ++e) {
            float z = fmaf(dist[e], wd, fmaf(cosv[e], wc, bb));
            float g = 0.5f * z * (1.f + erff(z * 0.70710678118654752f)); // exact gelu
            acc[e] = fmaf(g, wv, acc[e]);
        }
    }
    #pragma unroll
    for (int e = 0; e < 4; ++e) acc[e] = wave_sum(acc[e]);

    float b2v = b2[0];
    float muv[4];
    #pragma unroll
    for (int e = 0; e < 4; ++e) {
        float a = acc[e] + b2v;
        float sp = fmaxf(a, 0.f) + log1pf(expf(-fabsf(a)));  // stable softplus
        muv[e] = fminf(sp + 1e-5f, MU_MAX_);
    }
    if (lane == 0) {
        float* mB = mu + (size_t)b * EDGES_;
        mB[t0] = muv[0];                               // t0 <= L-2 always
        if (t0 < L_ - 2) {
            mB[(L_ - 1) + t0] = muv[1];
            mB[t0 + 1] = muv[2];
            if (t0 + 1 < L_ - 2) mB[(L_ - 1) + t0 + 1] = muv[3];
        }
    }
}

// ---------------- per-row 7-point stencil coefficients from mu halo ----------
static __device__ __forceinline__ void row_coeffs(
    int p, const float* __restrict__ mp, float coef, float C[7], float e[3])
{
    float m1a[8];
    #pragma unroll
    for (int j = 0; j < 8; ++j) {
        int u = p - 4 + j;
        m1a[j] = (u >= 0 && u < L_ - 1) ? mp[u] : 0.f;
    }
    float m2a[9];
    #pragma unroll
    for (int j = 0; j < 9; ++j) {
        int u = p - 5 + j;
        m2a[j] = (u >= 0 && u < L_ - 2) ? mp[(L_ - 1) + u] : 0.f;
    }
    float invv[7];
    #pragma unroll
    for (int d = 0; d < 7; ++d) {
        int u = p - 3 + d;
        if (u < 0 || u >= L_) { invv[d] = 0.f; }
        else {
            float deg = m1a[d + 1] + m1a[d] + m2a[d + 2] + m2a[d];
            invv[d] = 1.f / sqrtf(fmaxf(deg, 1e-6f));
        }
    }
    float gwv[3];
    gwv[0] = (p == 0) ? 0.f : LAM_;
    gwv[2] = (p == L_ - 1) ? 0.f : LAM_;
    gwv[1] = 1.f - 2.f * LAM_ + ((p == 0 || p == L_ - 1) ? LAM_ : 0.f);
    #pragma unroll
    for (int d = 0; d < 7; ++d) C[d] = 0.f;
    #pragma unroll
    for (int i = 0; i < 3; ++i) {            // s1 row k = p-1+i
        float g = gwv[i];
        float wm2 = m2a[i + 2] * invv[i + 2] * invv[i];
        float wm1 = m1a[i + 2] * invv[i + 2] * invv[i + 1];
        float wp1 = m1a[i + 3] * invv[i + 2] * invv[i + 3];
        float wp2 = m2a[i + 4] * invv[i + 2] * invv[i + 4];
        float wsum = wm2 + wm1 + wp1 + wp2;
        C[i]     = fmaf(g * coef, wm2, C[i]);
        C[i + 1] = fmaf(g * coef, wm1, C[i + 1]);
        C[i + 2] = fmaf(g, fmaf(-coef, wsum, 1.f), C[i + 2]);
        C[i + 3] = fmaf(g * coef, wp1, C[i + 3]);
        C[i + 4] = fmaf(g * coef, wp2, C[i + 4]);
        e[i] = g * coef;
    }
}

// ---------------- residual + LayerNorm of one row held in registers ----------
static __device__ __forceinline__ void ln_store(
    const float4 rr[3], const float* __restrict__ hrow,
    const float* __restrict__ gamma, const float* __restrict__ beta,
    float* __restrict__ orow, int lane)
{
    float sum = 0.f, sq = 0.f;
    float4 v[3];
    #pragma unroll
    for (int ch = 0; ch < 3; ++ch) {
        int off = ch * 64 + lane;
        float4 h = ((const float4*)hrow)[off];
        float4 x = rr[ch];
        x.x += h.x; x.y += h.y; x.z += h.z; x.w += h.w;
        v[ch] = x;
        sum += x.x + x.y + x.z + x.w;
        sq  += x.x * x.x + x.y * x.y + x.z * x.z + x.w * x.w;
    }
    sum = wave_sum(sum); sq = wave_sum(sq);
    float mean = sum * (1.f / H_);
    float var  = sq * (1.f / H_) - mean * mean;
    float rs = 1.f / sqrtf(var + 1e-5f);
    #pragma unroll
    for (int ch = 0; ch < 3; ++ch) {
        int off = ch * 64 + lane;
        float4 g4 = ((const float4*)gamma)[off];
        float4 b4 = ((const float4*)beta)[off];
        float4 o;
        o.x = (v[ch].x - mean) * rs * g4.x + b4.x;
        o.y = (v[ch].y - mean) * rs * g4.y + b4.y;
        o.z = (v[ch].z - mean) * rs * g4.z + b4.z;
        o.w = (v[ch].w - mean) * rs * g4.w + b4.w;
        ((float4*)orow)[off] = o;
    }
}

// ---------------- quad update: each wave computes rows t0..t0+3 ---------------
// 10 src + 6 q row-reads for 4 outputs (4 reads/row vs 6 paired). mu halo
// loaded ONCE per wave (23 scalars) and deg^-1/2 computed over a shared
// window; per-row coefficient FP order identical to row_coeffs (verified
// index mapping: row r term i uses M1/M2[r+i+k], IV[r+i+k]).
__global__ __launch_bounds__(256) void upd_quad_kernel(
    const float* __restrict__ src, const float* __restrict__ q,
    const float* __restrict__ mu, float* __restrict__ dst, float coef)
{
    int blk = blockIdx.x;
    int chunk = (blk & 7) * ((B_ * L_ / 16) / 8) + (blk >> 3);  // 2048, bijective
    int b = chunk >> 7;                      // 128 blocks per batch
    int p0 = (chunk & 127) * 16;
    int w = threadIdx.x >> 6, lane = threadIdx.x & 63;
    int t0 = p0 + 4 * w;                     // rows t0..t0+3 (always valid)

    const float* mp = mu + (size_t)b * EDGES_;
    float M1[11], M2[12];
    #pragma unroll
    for (int j = 0; j < 11; ++j) {
        int u = t0 - 4 + j;
        M1[j] = (u >= 0 && u < L_ - 1) ? mp[u] : 0.f;
    }
    #pragma unroll
    for (int j = 0; j < 12; ++j) {
        int u = t0 - 5 + j;
        M2[j] = (u >= 0 && u < L_ - 2) ? mp[(L_ - 1) + u] : 0.f;
    }
    float IV[10];
    #pragma unroll
    for (int d = 0; d < 10; ++d) {
        int u = t0 - 3 + d;
        if (u < 0 || u >= L_) { IV[d] = 0.f; }
        else {
            float deg = M1[d + 1] + M1[d] + M2[d + 2] + M2[d];
            IV[d] = 1.f / sqrtf(fmaxf(deg, 1e-6f));
        }
    }
    float C[4][7], e[4][3];
    #pragma unroll
    for (int r = 0; r < 4; ++r) {
        int p = t0 + r;
        float gwv[3];
        gwv[0] = (p == 0) ? 0.f : LAM_;
        gwv[2] = (p == L_ - 1) ? 0.f : LAM_;
        gwv[1] = 1.f - 2.f * LAM_ + ((p == 0 || p == L_ - 1) ? LAM_ : 0.f);
        #pragma unroll
        for (int d = 0; d < 7; ++d) C[r][d] = 0.f;
        #pragma unroll
        for (int i = 0; i < 3; ++i) {
            int j = r + i;
            float g = gwv[i];
            float wm2 = M2[j + 2] * IV[j + 2] * IV[j];
            float wm1 = M1[j + 2] * IV[j + 2] * IV[j + 1];
            float wp1 = M1[j + 3] * IV[j + 2] * IV[j + 3];
            float wp2 = M2[j + 4] * IV[j + 2] * IV[j + 4];
            float wsum = wm2 + wm1 + wp1 + wp2;
            C[r][i]     = fmaf(g * coef, wm2, C[r][i]);
            C[r][i + 1] = fmaf(g * coef, wm1, C[r][i + 1]);
            C[r][i + 2] = fmaf(g, fmaf(-coef, wsum, 1.f), C[r][i + 2]);
            C[r][i + 3] = fmaf(g * coef, wp1, C[r][i + 3]);
            C[r][i + 4] = fmaf(g * coef, wp2, C[r][i + 4]);
            e[r][i] = g * coef;
        }
    }

    const float* sB = src + (size_t)b * L_ * H_;
    const float* qB = q + (size_t)b * L_ * H_;
    const float* sp[10];
    #pragma unroll
    for (int u = 0; u < 10; ++u)
        sp[u] = sB + (size_t)min(max(t0 - 3 + u, 0), L_ - 1) * H_;
    const float* qp[6];
    #pragma unroll
    for (int u = 0; u < 6; ++u)
        qp[u] = qB + (size_t)min(max(t0 - 1 + u, 0), L_ - 1) * H_;

    float* dA = dst + ((size_t)b * L_ + t0) * H_;
    #pragma unroll
    for (int ch = 0; ch < 3; ++ch) {
        int off = ch * 64 + lane;
        float4 S[10], Q[6];
        #pragma unroll
        for (int u = 0; u < 10; ++u) S[u] = ((const float4*)sp[u])[off];
        #pragma unroll
        for (int u = 0; u < 6; ++u) Q[u] = ((const float4*)qp[u])[off];
        #pragma unroll
        for (int r = 0; r < 4; ++r) {
            float4 a = {0.f, 0.f, 0.f, 0.f};
            #pragma unroll
            for (int d = 0; d < 7; ++d) fma4(a, C[r][d], S[r + d]);
            #pragma unroll
            for (int i = 0; i < 3; ++i) fma4(a, e[r][i], Q[r + i]);
            ((float4*)(dA + (size_t)r * H_))[off] = a;
        }
    }
}

// ---------------- paired update (LN step only) --------------------------------
template <int LN>
__global__ __launch_bounds__(256) void upd_pair_kernel(
    const float* __restrict__ src, const float* __restrict__ q,
    const float* __restrict__ mu, float* __restrict__ dst,
    const float* __restrict__ hidden, const float* __restrict__ gamma,
    const float* __restrict__ beta, float* __restrict__ lnout, float coef)
{
    int blk = blockIdx.x;
    int chunk = (blk & 7) * ((B_ * L_ / 8) / 8) + (blk >> 3);   // bijective
    int b = chunk >> 8;                      // 256 blocks per batch
    int p0 = (chunk & 255) * 8;
    int w = threadIdx.x >> 6, lane = threadIdx.x & 63;
    int t0 = p0 + 2 * w;                     // rows t0, t0+1 (always valid)

    const float* mp = mu + (size_t)b * EDGES_;
    const float* sB = src + (size_t)b * L_ * H_;
    const float* qB = q + (size_t)b * L_ * H_;

    float CA[7], eA[3], CB[7], eB[3];
    row_coeffs(t0, mp, coef, CA, eA);
    row_coeffs(t0 + 1, mp, coef, CB, eB);

    const float* sp[8];
    #pragma unroll
    for (int u = 0; u < 8; ++u) {
        int g = min(max(t0 - 3 + u, 0), L_ - 1);
        sp[u] = sB + (size_t)g * H_;
    }
    const float* qp[4];
    #pragma unroll
    for (int u = 0; u < 4; ++u) {
        int g = min(max(t0 - 1 + u, 0), L_ - 1);
        qp[u] = qB + (size_t)g * H_;
    }

    float* dA = dst + ((size_t)b * L_ + t0) * H_;
    float4 keepA[3], keepB[3];
    #pragma unroll
    for (int ch = 0; ch < 3; ++ch) {
        int off = ch * 64 + lane;
        float4 S[8], Q[4];
        #pragma unroll
        for (int u = 0; u < 8; ++u) S[u] = ((const float4*)sp[u])[off];
        #pragma unroll
        for (int u = 0; u < 4; ++u) Q[u] = ((const float4*)qp[u])[off];
        float4 a = {0.f, 0.f, 0.f, 0.f}, c2 = {0.f, 0.f, 0.f, 0.f};
        #pragma unroll
        for (int d = 0; d < 7; ++d) { fma4(a, CA[d], S[d]); fma4(c2, CB[d], S[d + 1]); }
        #pragma unroll
        for (int i = 0; i < 3; ++i) { fma4(a, eA[i], Q[i]); fma4(c2, eB[i], Q[i + 1]); }
        ((float4*)dA)[off] = a;
        ((float4*)(dA + H_))[off] = c2;
        if (LN) { keepA[ch] = a; keepB[ch] = c2; }
    }

    if (LN) {
        size_t rowA = (size_t)b * L_ + t0;
        ln_store(keepA, hidden + rowA * H_, gamma, beta, lnout + rowA * H_, lane);
        ln_store(keepB, hidden + (rowA + 1) * H_, gamma, beta,
                 lnout + (rowA + 1) * H_, lane);
    }
}

// ---------------- energy ----------------
__global__ void zero_energy_kernel(float* __restrict__ e) {
    if (threadIdx.x < B_) e[threadIdx.x] = 0.f;
}

#define EPW 16
__global__ __launch_bounds__(256) void energy_kernel(
    const float* __restrict__ state, const int* __restrict__ ei, const int* __restrict__ ej,
    const float* __restrict__ mu, float* __restrict__ energy, int E)
{
    __shared__ float red[4];
    int wib = threadIdx.x >> 6;
    int lane = threadIdx.x & 63;
    int nchunk = (E + 63) / 64;
    int b = blockIdx.x / nchunk;
    int chunk = blockIdx.x - b * nchunk;
    int e0 = chunk * 64 + wib * EPW;
    const float* base = state + (size_t)b * L_ * H_;
    const float* muB = mu + (size_t)b * E;
    float part = 0.f;
    for (int k = 0; k < EPW; ++k) {
        int e = e0 + k;
        if (e >= E) break;
        int i = ei[e], j = ej[e];
        const float4* ri = (const float4*)(base + (size_t)i * H_);
        const float4* rj = (const float4*)(base + (size_t)j * H_);
        float s = 0.f;
        #pragma unroll
        for (int it = 0; it < 3; ++it) {
            float4 xi = ri[it * 64 + lane], xj = rj[it * 64 + lane];
            float dx = xi.x - xj.x, dy = xi.y - xj.y, dz = xi.z - xj.z, dw = xi.w - xj.w;
            s += dx*dx + dy*dy + dz*dz + dw*dw;
        }
        s = wave_sum(s);
        part += muB[e] * s;
    }
    if (lane == 0) red[wib] = part;
    __syncthreads();
    if (threadIdx.x == 0)
        atomicAdd(energy + b, 0.5f * (red[0] + red[1] + red[2] + red[3]));
}

extern "C" void kernel_launch(void* const* d_in, const int* in_sizes, int n_in,
                              void* d_out, int out_size, void* d_ws, size_t ws_size,
                              hipStream_t stream)
{
    const float* hidden = (const float*)d_in[0];
    // d_in[1] attention_mask: all ones, unused by the reference math
    const float* w1 = (const float*)d_in[2];
    const float* b1 = (const float*)d_in[3];
    const float* w2 = (const float*)d_in[4];
    const float* b2 = (const float*)d_in[5];
    const float* wq = (const float*)d_in[6];
    const float* bq = (const float*)d_in[7];
    const float* gamma = (const float*)d_in[8];
    const float* beta  = (const float*)d_in[9];
    const int* ei = (const int*)d_in[10];
    const int* ej = (const int*)d_in[11];
    int E = in_sizes[10];   // 2L-3 = 4093

    const size_t BLH = (size_t)B_ * L_ * H_;
    float* out = (float*)d_out;
    float* energy = out + BLH;   // outputs concatenated: out (B,L,H) then energy (B,)

    // workspace: q | bufA | bufB | mu | wt
    float* q    = (float*)d_ws;
    float* bufA = q + BLH;
    float* bufB = bufA + BLH;
    float* mu   = bufB + BLH;
    ushort* Abf = (ushort*)bufA;         // aliases bufA (dead after gemm)
    ushort* wt  = (ushort*)(mu + (size_t)B_ * EDGES_);

    int n8 = (int)(BLH / 8);
    conv_bf16_kernel<<<(n8 + 255) / 256, 256, 0, stream>>>(hidden, Abf, n8);
    conv_wqt_kernel<<<dim3(H_ / 64, H_ / 64), 256, 0, stream>>>(wq, wt);
    gemm_q_kernel<<<(B_ * L_ / GBM) * (H_ / GBN), 256, 0, stream>>>(Abf, wt, bq, q);
    zero_energy_kernel<<<1, 64, 0, stream>>>(energy);

    const int NBP = B_ * L_ / 8;     // mu grid: one wave per 2 rows
    const int NBQ = B_ * L_ / 16;    // quad update grid: one wave per 4 rows
    float coef = 0.1f;               // ETA * 0.9^step

    // step 0: hidden -> bufA
    mu_pair_kernel<<<NBP, 256, 0, stream>>>(hidden, w1, b1, w2, b2, mu);
    upd_quad_kernel<<<NBQ, 256, 0, stream>>>(hidden, q, mu, bufA, coef);
    coef *= 0.9f;
    // step 1: bufA -> bufB
    mu_pair_kernel<<<NBP, 256, 0, stream>>>(bufA, w1, b1, w2, b2, mu);
    upd_quad_kernel<<<NBQ, 256, 0, stream>>>(bufA, q, mu, bufB, coef);
    coef *= 0.9f;
    // step 2: bufB -> bufA
    mu_pair_kernel<<<NBP, 256, 0, stream>>>(bufB, w1, b1, w2, b2, mu);
    upd_quad_kernel<<<NBQ, 256, 0, stream>>>(bufB, q, mu, bufA, coef);
    coef *= 0.9f;
    // step 3: bufA -> bufB, fused residual+LN (energy needs mu_3 = mu(bufA))
    mu_pair_kernel<<<NBP, 256, 0, stream>>>(bufA, w1, b1, w2, b2, mu);
    upd_pair_kernel<1><<<NBP, 256, 0, stream>>>(bufA, q, mu, bufB,
        hidden, gamma, beta, out, coef);

    int nchunk = (E + 63) / 64;
    energy_kernel<<<B_ * nchunk, 256, 0, stream>>>(bufB, ei, ej, mu, energy, E);
}